// Round 16
// baseline (166.883 us; speedup 1.0000x reference)
//
#include <hip/hip_runtime.h>
#include <hip/hip_bf16.h>

// Problem constants
#define LNUM 8
#define ENUM 8
#define DDIM 256
#define BSZ  16384
#define H1N  64
#define H2N  32

#define BT   32     // rows per block  (grid 512 -> 2 blocks/CU)
#define NTHR 256    // 4 waves (256-thread shape compiles to ~100-120 VGPR)

// LDS pitches (u16 elements); odd 16B-granule strides -> conflict-light
#define PX   264    // x tile (D + 8)
#define PH1  72     // h1 tile pitch (H1 + 8)   [row][feat]
#define PH2  40     // h2 tile pitch (H2 + 8)   [row][feat]
#define PSW  9      // softmax weights pitch (floats)

// ws element offsets (u16 elems) for fragment-ordered weights
#define WS1_OFF 0           // 64 steps * 16384 elems
#define WS2_OFF 1048576     // 64 steps * 2048
#define WS3_OFF 1179648     // 64 steps * 8192

typedef float f32x4 __attribute__((ext_vector_type(4)));
typedef unsigned short u16x8 __attribute__((ext_vector_type(8)));
typedef unsigned short u16x4 __attribute__((ext_vector_type(4)));
typedef __bf16 bf16x8 __attribute__((ext_vector_type(8)));

#define Z4 ((f32x4){0.f, 0.f, 0.f, 0.f})

// f32 -> bf16 RTNE via native cast (compiler pairs into v_cvt_pk_bf16_f32).
static __device__ __forceinline__ unsigned short f2bf(float f) {
    __bf16 h = (__bf16)f;
    return __builtin_bit_cast(unsigned short, h);
}

// D[m][n] = sum_k A[m][k]*B[n][k] + C : A supplies m, B supplies n, frags are
// symmetric [idx16][K] -> swapping args transposes the output tile.
static __device__ __forceinline__ f32x4 mfma16(u16x8 a, u16x8 b, f32x4 c) {
    return __builtin_amdgcn_mfma_f32_16x16x32_bf16(
        __builtin_bit_cast(bf16x8, a), __builtin_bit_cast(bf16x8, b), c, 0, 0, 0);
}

// Barrier with lgkmcnt-only drain: LDS producer/consumer ordering preserved,
// in-flight GLOBAL loads are NOT drained (vs __syncthreads' vmcnt(0)).
// Safe: all inter-wave data flows through LDS; no global stores in the loop.
// HW-validated rounds 2/4/5/6/7/8/12/13/14.
static __device__ __forceinline__ void lbar() {
    asm volatile("s_waitcnt lgkmcnt(0)" ::: "memory");
    __builtin_amdgcn_s_barrier();
    asm volatile("" ::: "memory");
}

// ---------------------------------------------------------------------------
// Kernel 1: fp32 weights -> bf16 B-fragment layout. Unchanged.
// Fragment: 64 lanes x 8 elems; slot (q*16+r) holds W[n0+r][k0+q*8 .. +7].
// ---------------------------------------------------------------------------
__global__ __launch_bounds__(256) void cvt_w_frag(
    const float* __restrict__ w1, const float* __restrict__ w2,
    const float* __restrict__ w3, unsigned short* __restrict__ ws)
{
    int gid = blockIdx.x * 256 + threadIdx.x;
    const float* src;
    unsigned short* dst;
    if (gid < 131072) {                          // W1: [s][n(64)][k(256)]
        int s = gid >> 11, rem = gid & 2047;
        int n = rem >> 5, kc = rem & 31;
        int nt = n >> 4, r = n & 15, kt = kc >> 2, q = kc & 3;
        src = w1 + (size_t)gid * 8;
        dst = ws + WS1_OFF + (size_t)s * 16384 + nt * 4096 + kt * 512 + (q * 16 + r) * 8;
    } else if (gid < 147456) {                   // W2: [s][n(32)][k(64)]
        int g = gid - 131072;
        int s = g >> 8, rem = g & 255;
        int n = rem >> 3, kc = rem & 7;
        int n2 = n >> 4, r = n & 15, kt = kc >> 2, q = kc & 3;
        src = w2 + (size_t)g * 8;
        dst = ws + WS2_OFF + (size_t)s * 2048 + n2 * 1024 + kt * 512 + (q * 16 + r) * 8;
    } else {                                     // W3: [s][n(256)][k(32)]
        int g = gid - 147456;
        int s = g >> 10, rem = g & 1023;
        int n = rem >> 2, q = rem & 3;
        int nt = n >> 4, r = n & 15;
        src = w3 + (size_t)g * 8;
        dst = ws + WS3_OFF + (size_t)s * 8192 + nt * 512 + (q * 16 + r) * 8;
    }
    float4 a = *(const float4*)src;
    float4 b = *(const float4*)(src + 4);
    u16x8 p;
    p[0] = f2bf(a.x); p[1] = f2bf(a.y); p[2] = f2bf(a.z); p[3] = f2bf(a.w);
    p[4] = f2bf(b.x); p[5] = f2bf(b.y); p[6] = f2bf(b.z); p[7] = f2bf(b.w);
    *(u16x8*)dst = p;
}

// ---------------------------------------------------------------------------
// Kernel 2: fused 8-layer x 8-expert MoE MLP — R14 structure (4 waves, wave
// wv owns experts {wv, wv+4} end-to-end through G1/G2, wave-private H1
// transpose, 2 barriers/layer, W3 rotation, softmax parity dbuf) with:
//  (a) Bias-split G3 fusion: G3 accumulates experts into AC2 (zero-init);
//      the bias blend (old acc_init: sum_e sw*b3) computes into ACC
//      INTERLEAVED per-expert inside the G3 loop; merged once at the end.
//      Breaks the ACC C-operand dependency that serialized ~450 VALU ops +
//      loads before G3's first MFMA each layer. Same fp32 math (bias added
//      last instead of first).
//  (b) W2 prefetch at G1-top: each expert's 4 W2 frags issue ~1200 cyc
//      before their G2 use (peak G1 liveness 112 < 128).
// ---------------------------------------------------------------------------
__global__ __launch_bounds__(NTHR, 2) void moe_fused(
    const float* __restrict__ src, const unsigned short* __restrict__ Wf,
    const float* __restrict__ b1, const float* __restrict__ b2,
    const float* __restrict__ b3, const float* __restrict__ masks,
    float* __restrict__ out)
{
    __shared__ __align__(16) unsigned short Xlds[BT * PX];        // 16896 B
    __shared__ __align__(16) unsigned short H1W[4][BT * PH1];     // 18432 B wave-private
    __shared__ __align__(16) unsigned short H2T[8][BT * PH2];     // 20480 B per-expert
    __shared__ float SWlds[2][BT * PSW];                          //  2304 B parity dbuf
    // total 58112 B -> 2 blocks/CU (116224 <= 163840)

    const int tid  = threadIdx.x;
    const int lane = tid & 63;
    const int wv   = tid >> 6;      // wave id 0..3: experts {wv, wv+4}; G3 col grp
    const int n15  = lane & 15;
    const int q    = lane >> 4;
    const int b0   = blockIdx.x * BT;

    const unsigned short* w3base = Wf + WS3_OFF + wv * 2048 + lane * 8;

    u16x8 xf[2][8];          // persistent x B-frags (dead during G3 + at mid-bar)
    f32x4 ACC[2][4];         // bias accumulator / final sum

    // Distributed softmax for layer l into SWlds[p]: each wave's lanes 0-7
    // handle rows wv*8 .. wv*8+7. Readers (G2(l), bias(l)) are >=1 barrier
    // after the write; stale readers of parity p are >=2 barriers before.
    auto stage_softmax = [&](int l, int p) {
        if (lane < 8) {
            int row = wv * 8 + lane;
            const float* mp = masks + ((size_t)l * BSZ + b0 + row) * ENUM;
            float4 m0 = *(const float4*)mp;
            float4 m1 = *(const float4*)(mp + 4);
            float mv[8] = {m0.x, m0.y, m0.z, m0.w, m1.x, m1.y, m1.z, m1.w};
            float mx = mv[0];
            #pragma unroll
            for (int e = 1; e < 8; ++e) mx = fmaxf(mx, mv[e]);
            float s = 0.f;
            #pragma unroll
            for (int e = 0; e < 8; ++e) { mv[e] = expf(mv[e] - mx); s += mv[e]; }
            float inv = 1.f / s;
            #pragma unroll
            for (int e = 0; e < 8; ++e) SWlds[p][row * PSW + e] = mv[e] * inv;
        }
    };

    auto xf_read = [&]() {
        #pragma unroll
        for (int mt = 0; mt < 2; ++mt)
            #pragma unroll
            for (int kt = 0; kt < 8; ++kt)
                xf[mt][kt] = *(const u16x8*)
                    &Xlds[(mt*16 + n15) * PX + q*8 + kt*32];
    };
    auto x_write = [&]() {
        #pragma unroll
        for (int mt = 0; mt < 2; ++mt)
            #pragma unroll
            for (int nt = 0; nt < 4; ++nt)
                #pragma unroll
                for (int rr = 0; rr < 4; ++rr)
                    Xlds[(mt*16 + q*4 + rr) * PX + wv*64 + nt*16 + n15] =
                        f2bf(ACC[mt][nt][rr]);
    };

    // ================= prologue =================
    #pragma unroll
    for (int i = 0; i < 4; ++i) {                // stage layer-0 x (bf16)
        int o = (i * NTHR + tid) * 8;
        int r = o >> 8, c = o & 255;
        const float* p = src + (size_t)(b0 + r) * DDIM + c;
        float4 f0 = *(const float4*)(p);
        float4 f1 = *(const float4*)(p + 4);
        u16x8 pk;
        pk[0] = f2bf(f0.x); pk[1] = f2bf(f0.y); pk[2] = f2bf(f0.z); pk[3] = f2bf(f0.w);
        pk[4] = f2bf(f1.x); pk[5] = f2bf(f1.y); pk[6] = f2bf(f1.z); pk[7] = f2bf(f1.w);
        *(u16x8*)&Xlds[r * PX + c] = pk;
    }
    stage_softmax(0, 0);
    __syncthreads();
    xf_read();

    // ================= layer loop =================
    #pragma unroll 1
    for (int l = 0; l < LNUM; ++l) {
        const int sbase = l * ENUM;

        // ===== G1+G2 for this wave's two experts (barrier-free) =====
        #pragma unroll
        for (int pe = 0; pe < 2; ++pe) {
            const int e = wv + pe * 4;
            const int s = sbase + e;

            // ---- W2 prefetch (consumed in G2, ~4 ft-blocks below) ----
            u16x8 w2f[2][2];
            {
                const unsigned short* p2 =
                    Wf + WS2_OFF + (size_t)s * 2048 + lane * 8;
                #pragma unroll
                for (int f2 = 0; f2 < 2; ++f2)
                    #pragma unroll
                    for (int kt = 0; kt < 2; ++kt)
                        w2f[f2][kt] = *(const u16x8*)(p2 + f2*1024 + kt*512);
            }

            // ---- G1: h1 = relu(x @ W1^T + b1), 4 feat-tiles ----
            // Batched w1f[8] loads (R8 schedule, best measured).
            // lane -> feats ft*16+q*4+rr, rows mt*16+n15 (transposed MFMA)
            #pragma unroll
            for (int ft = 0; ft < 4; ++ft) {
                u16x8 w1f[8];
                const unsigned short* p1 =
                    Wf + WS1_OFF + (size_t)s * 16384 + ft * 4096 + lane * 8;
                #pragma unroll
                for (int kt = 0; kt < 8; ++kt)
                    w1f[kt] = *(const u16x8*)(p1 + kt * 512);
                f32x4 a1[2] = {Z4, Z4};
                __builtin_amdgcn_s_setprio(1);
                #pragma unroll
                for (int kt = 0; kt < 8; ++kt) {
                    a1[0] = mfma16(w1f[kt], xf[0][kt], a1[0]);
                    a1[1] = mfma16(w1f[kt], xf[1][kt], a1[1]);
                }
                __builtin_amdgcn_s_setprio(0);
                const float4 bb1 = *(const float4*)(b1 + s * 64 + ft * 16 + q * 4);
                #pragma unroll
                for (int mt = 0; mt < 2; ++mt) {
                    u16x4 pk;
                    #pragma unroll
                    for (int rr = 0; rr < 4; ++rr)
                        pk[rr] = f2bf(fmaxf(a1[mt][rr] + bb1[rr], 0.f));
                    *(u16x4*)&H1W[wv][(mt*16 + n15) * PH1 + ft*16 + q*4] = pk;
                }
            }

            // ---- G2: h2 = relu(h1 @ W2^T + b2) * sw[e] ----
            // intra-wave H1W write->read: compiler-ordered lgkmcnt, no barrier
            {
                u16x8 h1f[2][2];
                #pragma unroll
                for (int mt = 0; mt < 2; ++mt)
                    #pragma unroll
                    for (int kt = 0; kt < 2; ++kt)
                        h1f[mt][kt] = *(const u16x8*)
                            &H1W[wv][(mt*16 + n15) * PH1 + q*8 + kt*32];
                f32x4 a2[2][2] = {{Z4, Z4}, {Z4, Z4}};
                #pragma unroll
                for (int f2 = 0; f2 < 2; ++f2)
                    #pragma unroll
                    for (int mt = 0; mt < 2; ++mt)
                        #pragma unroll
                        for (int kt = 0; kt < 2; ++kt)
                            a2[f2][mt] = mfma16(w2f[f2][kt], h1f[mt][kt], a2[f2][mt]);
                float swv[2];
                #pragma unroll
                for (int mt = 0; mt < 2; ++mt)
                    swv[mt] = SWlds[l & 1][(mt*16 + n15) * PSW + e];
                #pragma unroll
                for (int f2 = 0; f2 < 2; ++f2) {
                    const float4 bb2 = *(const float4*)(b2 + s * 32 + f2 * 16 + q * 4);
                    #pragma unroll
                    for (int mt = 0; mt < 2; ++mt) {
                        u16x4 pk;
                        #pragma unroll
                        for (int rr = 0; rr < 4; ++rr)
                            pk[rr] = f2bf(fmaxf(a2[f2][mt][rr] + bb2[rr], 0.f) * swv[mt]);
                        *(u16x4*)&H2T[e][(mt*16 + n15) * PH2 + f2*16 + q*4] = pk;
                    }
                }
            }
        }

        // ===== W3 prefetch for e=0: crosses the mid-layer barrier at the
        //       kernel's lowest-pressure point (xf dead here) =====
        u16x8 w3a[4], w3b[4];
        {
            const unsigned short* p3 = w3base + (size_t)sbase * 8192;
            #pragma unroll
            for (int nt = 0; nt < 4; ++nt)
                w3a[nt] = *(const u16x8*)(p3 + nt * 512);
        }

        lbar();                     // mid-layer barrier; W3(e=0) stays in flight

        // ===== next layer's softmax into the other parity buffer =====
        if (l < LNUM - 1) stage_softmax(l + 1, (l + 1) & 1);

        // ===== G3 fused with bias blend (bias-split) =====
        // AC2 accumulates the 8 experts' MFMAs; ACC accumulates the bias
        // sum_e sw[row][e]*b3[e][col] on the VALU, interleaved per expert so
        // it hides under MFMA latency and W3 load waits. Merged at the end.
        const float* b3l = b3 + (size_t)l * ENUM * DDIM;
        const int pl = l & 1;
        f32x4 AC2[2][4];
        #pragma unroll
        for (int mt = 0; mt < 2; ++mt)
            #pragma unroll
            for (int nt = 0; nt < 4; ++nt) { ACC[mt][nt] = Z4; AC2[mt][nt] = Z4; }

        #pragma unroll
        for (int e = 0; e < ENUM; ++e) {
            // issue NEXT expert's W3 loads before this expert's MFMAs
            if (e < ENUM - 1) {
                const unsigned short* p3 = w3base + (size_t)(sbase + e + 1) * 8192;
                u16x8* nxt = (e & 1) ? w3a : w3b;
                #pragma unroll
                for (int nt = 0; nt < 4; ++nt)
                    nxt[nt] = *(const u16x8*)(p3 + nt * 512);
            }
            const u16x8* cur = (e & 1) ? w3b : w3a;
            u16x8 h0  = *(const u16x8*)&H2T[e][(n15) * PH2 + q*8];
            u16x8 h1v = *(const u16x8*)&H2T[e][(16 + n15) * PH2 + q*8];
            #pragma unroll
            for (int nt = 0; nt < 4; ++nt) {
                AC2[0][nt] = mfma16(h0,  cur[nt], AC2[0][nt]);
                AC2[1][nt] = mfma16(h1v, cur[nt], AC2[1][nt]);
            }
            // bias contribution of expert e (VALU; independent of AC2 chain)
            float swe[2][4];
            #pragma unroll
            for (int mt = 0; mt < 2; ++mt)
                #pragma unroll
                for (int rr = 0; rr < 4; ++rr)
                    swe[mt][rr] = SWlds[pl][(mt*16 + q*4 + rr) * PSW + e];
            #pragma unroll
            for (int nt = 0; nt < 4; ++nt) {
                float bv = b3l[e * DDIM + wv*64 + nt*16 + n15];
                #pragma unroll
                for (int mt = 0; mt < 2; ++mt)
                    #pragma unroll
                    for (int rr = 0; rr < 4; ++rr)
                        ACC[mt][nt][rr] += swe[mt][rr] * bv;
            }
        }

        // merge: ACC = bias + expert sum
        #pragma unroll
        for (int mt = 0; mt < 2; ++mt)
            #pragma unroll
            for (int nt = 0; nt < 4; ++nt)
                ACC[mt][nt] += AC2[mt][nt];

        // ===== layer transition (single barrier) =====
        if (l < LNUM - 1) {
            x_write();
            lbar();
            xf_read();
        }
    }

    // ================= final store (fp32) =================
    #pragma unroll
    for (int mt = 0; mt < 2; ++mt)
        #pragma unroll
        for (int nt = 0; nt < 4; ++nt)
            #pragma unroll
            for (int rr = 0; rr < 4; ++rr)
                out[(size_t)(b0 + mt*16 + q*4 + rr) * DDIM
                    + wv*64 + nt*16 + n15] = ACC[mt][nt][rr];
}

extern "C" void kernel_launch(void* const* d_in, const int* in_sizes, int n_in,
                              void* d_out, int out_size, void* d_ws, size_t ws_size,
                              hipStream_t stream) {
    const float* src   = (const float*)d_in[0];
    const float* W1    = (const float*)d_in[1];
    const float* b1    = (const float*)d_in[2];
    const float* W2    = (const float*)d_in[3];
    const float* b2    = (const float*)d_in[4];
    const float* W3    = (const float*)d_in[5];
    const float* b3    = (const float*)d_in[6];
    const float* masks = (const float*)d_in[7];
    float* out = (float*)d_out;
    unsigned short* ws = (unsigned short*)d_ws;   // needs 3,407,872 B

    hipLaunchKernelGGL(cvt_w_frag, dim3(832), dim3(256), 0, stream, W1, W2, W3, ws);
    hipLaunchKernelGGL(moe_fused, dim3(BSZ / BT), dim3(NTHR), 0, stream,
                       src, ws, b1, b2, b3, masks, out);
}